// Round 1
// 672.722 us; speedup vs baseline: 1.1230x; 1.1230x over previous
//
#include <hip/hip_runtime.h>
#include <stdint.h>

typedef __attribute__((ext_vector_type(4))) float f32x4;
typedef _Float16 half8 __attribute__((ext_vector_type(8)));

// ---------------- CSR build via bucket binning ----------------
// bucket = dst >> 8 (256 nodes/bucket). Scattered writes become L2-window-local:
//  k_bhist : per-block LDS bucket histogram -> global bucket counts
//  k_bscan : serial scan of ~391 bucket counts -> bbase/gcur
//  k_bin   : per-block LDS bin; bulk-reserve per (block,bucket); burst-write packed edges
//  k_nhist : one block per bucket; LDS per-node degree hist -> deg (contiguous write)
//  k_bfill : one block per bucket; LDS cursors; ssrc writes confined to ~16KB window

#define BIN_CHUNK 8192   // edges per block, 32/thread
#define MAXB 512         // >= nb = ceil(N/256)

__global__ __launch_bounds__(256) void k_bhist(const int* __restrict__ dst,
                                               int* __restrict__ bcnt, int E) {
    __shared__ int lh[MAXB];
    for (int i = threadIdx.x; i < MAXB; i += 256) lh[i] = 0;
    __syncthreads();
    const int base = blockIdx.x * BIN_CHUNK;
#pragma unroll 4
    for (int i = 0; i < BIN_CHUNK / 256; i++) {
        int e = base + i * 256 + threadIdx.x;
        if (e < E) atomicAdd(&lh[dst[e] >> 8], 1);
    }
    __syncthreads();
    for (int i = threadIdx.x; i < MAXB; i += 256)
        if (lh[i]) atomicAdd(&bcnt[i], lh[i]);
}

__global__ void k_bscan(const int* __restrict__ bcnt, int* __restrict__ bbase,
                        int* __restrict__ gcur, int nb) {
    if (threadIdx.x == 0 && blockIdx.x == 0) {
        int run = 0;
        for (int i = 0; i < nb; i++) { bbase[i] = run; gcur[i] = run; run += bcnt[i]; }
        bbase[nb] = run;
    }
}

__global__ __launch_bounds__(256) void k_bin(const int* __restrict__ src,
                                             const int* __restrict__ dst,
                                             int* __restrict__ gcur,
                                             unsigned* __restrict__ ebuf, int E) {
    __shared__ int lh[MAXB];
    __shared__ int lcur[MAXB];
    for (int i = threadIdx.x; i < MAXB; i += 256) lh[i] = 0;
    __syncthreads();
    const int base = blockIdx.x * BIN_CHUNK;
#pragma unroll 4
    for (int i = 0; i < BIN_CHUNK / 256; i++) {
        int e = base + i * 256 + threadIdx.x;
        if (e < E) atomicAdd(&lh[dst[e] >> 8], 1);
    }
    __syncthreads();
    for (int i = threadIdx.x; i < MAXB; i += 256)
        lcur[i] = lh[i] ? atomicAdd(&gcur[i], lh[i]) : 0;
    __syncthreads();
#pragma unroll 4
    for (int i = 0; i < BIN_CHUNK / 256; i++) {
        int e = base + i * 256 + threadIdx.x;
        if (e < E) {
            int d = dst[e];
            int pos = atomicAdd(&lcur[d >> 8], 1);
            // N < 2^24: pack src in low 24 bits, dst low byte in high 8 bits
            ebuf[pos] = (unsigned)src[e] | ((unsigned)(d & 255) << 24);
        }
    }
}

__global__ __launch_bounds__(256) void k_nhist(const unsigned* __restrict__ ebuf,
                                               const int* __restrict__ bbase,
                                               int* __restrict__ deg, int N) {
    __shared__ int cnt[256];
    cnt[threadIdx.x] = 0;
    __syncthreads();
    const int b = blockIdx.x;
    const int lo = bbase[b], hi = bbase[b + 1];
    for (int e = lo + threadIdx.x; e < hi; e += 256)
        atomicAdd(&cnt[ebuf[e] >> 24], 1);
    __syncthreads();
    int n = (b << 8) + threadIdx.x;
    if (n < N) deg[n] = cnt[threadIdx.x];
}

__global__ __launch_bounds__(256) void k_bfill(const unsigned* __restrict__ ebuf,
                                               const int* __restrict__ bbase,
                                               const int* __restrict__ rowptr,
                                               int* __restrict__ ssrc, int N) {
    __shared__ int lc[256];
    const int b = blockIdx.x;
    const int nbase = b << 8;
    int n = nbase + threadIdx.x;
    lc[threadIdx.x] = (n < N) ? rowptr[n] : 0;
    __syncthreads();
    const int lo = bbase[b], hi = bbase[b + 1];
    for (int e = lo + threadIdx.x; e < hi; e += 256) {
        unsigned v = ebuf[e];
        int pos = atomicAdd(&lc[v >> 24], 1);
        ssrc[pos] = (int)(v & 0xFFFFFFu >> 8 << 8 | (v & 0xFFu)); // low 24 bits
    }
}

// ---------------- rowptr scan (unchanged structure) ----------------

__global__ void k_scan1(int* __restrict__ buf, int* __restrict__ chunkSum, int N) {
    const int t = threadIdx.x;
    const int base = blockIdx.x * 2048 + t * 8;
    int v[8];
    int s = 0;
#pragma unroll
    for (int i = 0; i < 8; i++) {
        int idx = base + i;
        v[i] = (idx < N) ? buf[idx] : 0;
        s += v[i];
    }
    __shared__ int sh[256];
    sh[t] = s;
    __syncthreads();
    for (int off = 1; off < 256; off <<= 1) {
        int add = (t >= off) ? sh[t - off] : 0;
        __syncthreads();
        sh[t] += add;
        __syncthreads();
    }
    int excl = sh[t] - s;
    int run = excl;
#pragma unroll
    for (int i = 0; i < 8; i++) {
        int idx = base + i;
        if (idx < N) buf[idx] = run;
        run += v[i];
    }
    if (t == 255) chunkSum[blockIdx.x] = sh[255];
}

__global__ void k_scan2(const int* __restrict__ chunkSum, int* __restrict__ chunkOff,
                        int nch, int* __restrict__ rowptrN) {
    if (threadIdx.x == 0 && blockIdx.x == 0) {
        int run = 0;
        for (int i = 0; i < nch; i++) { chunkOff[i] = run; run += chunkSum[i]; }
        *rowptrN = run;
    }
}

__global__ void k_scan3(int* __restrict__ rowptr, const int* __restrict__ chunkOff, int N) {
    int i = blockIdx.x * 256 + threadIdx.x;
    if (i < N) rowptr[i] += chunkOff[i >> 11];
}

// ---------------- weight prep: Wt[n][k] = f16( n<NCOL ? Wl[k][n] : Wr[k][n-NCOL] ) ----------------

template <int K, int NCOLT>
__global__ void k_wprep(const float* __restrict__ Wl, const float* __restrict__ Wr,
                        _Float16* __restrict__ Wt) {
    constexpr int NCOL = NCOLT / 2;
    int i = blockIdx.x * 256 + threadIdx.x;
    if (i < K * NCOLT) {
        int n = i / K, k = i - n * K;
        float v = (n < NCOL) ? Wl[(size_t)k * NCOL + n] : Wr[(size_t)k * NCOL + (n - NCOL)];
        Wt[i] = (_Float16)v;
    }
}

// ---------------- MFMA GEMM: [Cl|Cr] = A @ [Wl|Wr] (f16 in, fp32 acc, f16 out) ----------------

template <int K, int NCOLT, bool AF32>
__global__ __launch_bounds__(256) void k_gemmM(const void* __restrict__ Av,
                                               const _Float16* __restrict__ Wt,
                                               const float* __restrict__ bias,
                                               _Float16* __restrict__ Cl,
                                               _Float16* __restrict__ Cr, int M) {
    constexpr int NCOL = NCOLT / 2;
    constexpr int WC = NCOLT / 4;
    constexpr int NT = WC / 16;
    const int tid = threadIdx.x;
    const int lane = tid & 63;
    const int wave = tid >> 6;
    const int quad = lane >> 4;
    const int l16 = lane & 15;
    const int m0 = blockIdx.x * 64;
    const int colbase = wave * WC;

    f32x4 acc[4][NT];
#pragma unroll
    for (int rg = 0; rg < 4; rg++)
#pragma unroll
        for (int t = 0; t < NT; t++) acc[rg][t] = (f32x4){0.f, 0.f, 0.f, 0.f};

#pragma unroll
    for (int k0 = 0; k0 < K; k0 += 32) {
        half8 a[4];
#pragma unroll
        for (int rg = 0; rg < 4; rg++) {
            int m = m0 + rg * 16 + l16;
            if (AF32) {
                f32x4 u0 = {0.f, 0.f, 0.f, 0.f}, u1 = {0.f, 0.f, 0.f, 0.f};
                if (m < M) {
                    const float* ap = (const float*)Av + (size_t)m * K + k0 + quad * 8;
                    u0 = *(const f32x4*)ap;
                    u1 = *(const f32x4*)(ap + 4);
                }
                a[rg] = (half8){(_Float16)u0[0], (_Float16)u0[1], (_Float16)u0[2], (_Float16)u0[3],
                                (_Float16)u1[0], (_Float16)u1[1], (_Float16)u1[2], (_Float16)u1[3]};
            } else {
                half8 az = {0, 0, 0, 0, 0, 0, 0, 0};
                a[rg] = (m < M)
                    ? *(const half8*)((const _Float16*)Av + (size_t)m * K + k0 + quad * 8)
                    : az;
            }
        }
        half8 b[NT];
#pragma unroll
        for (int t = 0; t < NT; t++)
            b[t] = *(const half8*)(Wt + (size_t)(colbase + t * 16 + l16) * K + k0 + quad * 8);
#pragma unroll
        for (int rg = 0; rg < 4; rg++)
#pragma unroll
            for (int t = 0; t < NT; t++)
                acc[rg][t] = __builtin_amdgcn_mfma_f32_16x16x32_f16(a[rg], b[t], acc[rg][t], 0, 0, 0);
    }

    const bool isR = (colbase >= NCOL);
#pragma unroll
    for (int t = 0; t < NT; t++) {
        int col = colbase + t * 16 + l16;
        float bv = isR ? bias[col - NCOL] : 0.f;
        _Float16* dst = isR ? (Cr + (col - NCOL)) : (Cl + col);
#pragma unroll
        for (int rg = 0; rg < 4; rg++) {
#pragma unroll
            for (int r = 0; r < 4; r++) {
                int row = m0 + rg * 16 + quad * 4 + r;
                if (row < M) dst[(size_t)row * NCOL] = (_Float16)(acc[rg][t][r] + bv);
            }
        }
    }
}

// ---------------- aggregation ----------------

template <int COUT, int MODE>
__global__ __launch_bounds__(256) void k_agg(const half8* __restrict__ xl,
                                             const half8* __restrict__ xr,
                                             const int* __restrict__ rowptr,
                                             const int* __restrict__ ssrc,
                                             float* __restrict__ outF1,
                                             float* __restrict__ outF2,
                                             _Float16* __restrict__ outH, int N) {
    constexpr int LPN = COUT / 16;
    constexpr int NPB = 256 / LPN;
    constexpr int C8 = COUT / 8;
    const int tid = threadIdx.x;
    const int c = tid % LPN;
    const int n = blockIdx.x * NPB + tid / LPN;
    if (n >= N) return;

    const int rp0 = rowptr[n];
    const int rp1 = rowptr[n + 1];
    float acc[16];
#pragma unroll
    for (int i = 0; i < 16; i++) acc[i] = 0.f;

    const size_t cb = (size_t)c * 2;
    int e = rp0;
    for (; e + 3 < rp1; e += 4) {
        int s0 = ssrc[e], s1 = ssrc[e + 1], s2 = ssrc[e + 2], s3 = ssrc[e + 3];
        half8 v0a = xl[(size_t)s0 * C8 + cb], v0b = xl[(size_t)s0 * C8 + cb + 1];
        half8 v1a = xl[(size_t)s1 * C8 + cb], v1b = xl[(size_t)s1 * C8 + cb + 1];
        half8 v2a = xl[(size_t)s2 * C8 + cb], v2b = xl[(size_t)s2 * C8 + cb + 1];
        half8 v3a = xl[(size_t)s3 * C8 + cb], v3b = xl[(size_t)s3 * C8 + cb + 1];
#pragma unroll
        for (int i = 0; i < 8; i++) {
            acc[i] += (float)v0a[i] + (float)v1a[i] + (float)v2a[i] + (float)v3a[i];
            acc[8 + i] += (float)v0b[i] + (float)v1b[i] + (float)v2b[i] + (float)v3b[i];
        }
    }
    for (; e < rp1; e++) {
        int s = ssrc[e];
        half8 va = xl[(size_t)s * C8 + cb], vb = xl[(size_t)s * C8 + cb + 1];
#pragma unroll
        for (int i = 0; i < 8; i++) {
            acc[i] += (float)va[i];
            acc[8 + i] += (float)vb[i];
        }
    }

    const int deg = rp1 - rp0;
    const float scale = 1.0f / (float)(deg > 1 ? deg : 1);
    half8 x0 = xr[(size_t)n * C8 + cb];
    half8 x1 = xr[(size_t)n * C8 + cb + 1];
    float res[16];
#pragma unroll
    for (int i = 0; i < 8; i++) {
        res[i] = acc[i] * scale + (float)x0[i];
        res[8 + i] = acc[8 + i] * scale + (float)x1[i];
    }

    const size_t ob = (size_t)n * COUT + (size_t)c * 16;
    if (MODE == 0) {
        half8 h0v, h1v;
#pragma unroll
        for (int i = 0; i < 8; i++) {
            h0v[i] = (_Float16)(res[i] > 0.f ? res[i] : 0.f);
            h1v[i] = (_Float16)(res[8 + i] > 0.f ? res[8 + i] : 0.f);
        }
        *(half8*)(outH + ob) = h0v;
        *(half8*)(outH + ob + 8) = h1v;
    } else if (MODE == 1) {
#pragma unroll
        for (int q = 0; q < 4; q++) {
            f32x4 v = {res[q * 4], res[q * 4 + 1], res[q * 4 + 2], res[q * 4 + 3]};
            *(f32x4*)(outF1 + ob + q * 4) = v;
            f32x4 z = {v[0] > 0.f ? v[0] : 0.f, v[1] > 0.f ? v[1] : 0.f,
                       v[2] > 0.f ? v[2] : 0.f, v[3] > 0.f ? v[3] : 0.f};
            *(f32x4*)(outF2 + ob + q * 4) = z;
        }
        half8 h0v, h1v;
#pragma unroll
        for (int i = 0; i < 8; i++) {
            h0v[i] = (_Float16)(res[i] > 0.f ? res[i] : 0.f);
            h1v[i] = (_Float16)(res[8 + i] > 0.f ? res[8 + i] : 0.f);
        }
        *(half8*)(outH + ob) = h0v;
        *(half8*)(outH + ob + 8) = h1v;
    } else {
#pragma unroll
        for (int q = 0; q < 4; q++) {
            f32x4 v = {res[q * 4], res[q * 4 + 1], res[q * 4 + 2], res[q * 4 + 3]};
            *(f32x4*)(outF1 + ob + q * 4) = v;
        }
    }
}

// ---------------- launch ----------------

extern "C" void kernel_launch(void* const* d_in, const int* in_sizes, int n_in,
                              void* d_out, int out_size, void* d_ws, size_t ws_size,
                              hipStream_t stream) {
    const float* x   = (const float*)d_in[0];
    const int*   ei  = (const int*)d_in[1];
    const float* Wl0 = (const float*)d_in[2];
    const float* Wr0 = (const float*)d_in[3];
    const float* b0  = (const float*)d_in[4];
    const float* Wl1 = (const float*)d_in[5];
    const float* Wr1 = (const float*)d_in[6];
    const float* b1  = (const float*)d_in[7];
    const float* Wl2 = (const float*)d_in[8];
    const float* Wr2 = (const float*)d_in[9];
    const float* b2  = (const float*)d_in[10];

    const int N = in_sizes[0] / 256;   // 100000
    const int E = in_sizes[1] / 2;     // 1600000
    const int* src = ei;
    const int* dst = ei + E;

    char* p = (char*)d_ws;
    auto alloc = [&](size_t bytes) -> void* {
        void* r = (void*)p;
        p += (bytes + 255) & ~(size_t)255;
        return r;
    };
    int*      rowptr   = (int*)alloc((size_t)(N + 1) * 4);
    int*      chunkSum = (int*)alloc(64 * 4);
    int*      chunkOff = (int*)alloc(64 * 4);
    int*      bcnt     = (int*)alloc(MAXB * 4);
    int*      bbase    = (int*)alloc((MAXB + 1) * 4);
    int*      gcur     = (int*)alloc(MAXB * 4);
    int*      ssrc     = (int*)alloc((size_t)E * 4);
    _Float16* xl       = (_Float16*)alloc((size_t)N * 128 * 2);
    _Float16* xr       = (_Float16*)alloc((size_t)N * 128 * 2);
    _Float16* h0       = (_Float16*)alloc((size_t)N * 128 * 2);
    _Float16* gb       = (_Float16*)alloc((size_t)N * 128 * 2);
    _Float16* Wt0      = (_Float16*)alloc((size_t)256 * 256 * 2);
    _Float16* Wt1      = (_Float16*)alloc((size_t)256 * 128 * 2);
    _Float16* Wt2      = (_Float16*)alloc((size_t)128 * 128 * 2);

    // ebuf (binned packed edges, E*4 bytes) aliases gb: dead before gb's first
    // write (layer-1 agg), stream-ordered so no hazard.
    unsigned* ebuf = (unsigned*)gb;

    float* out = (float*)d_out;
    float* x_final = out;                      // N*64
    float* out1    = out + (size_t)N * 64;     // N*128
    float* g       = out + (size_t)N * 192;    // N*128

    const int nb = (N + 255) >> 8;             // buckets of 256 nodes
    const int nbk = (E + BIN_CHUNK - 1) / BIN_CHUNK;

    // ---- CSR build (binned) ----
    hipMemsetAsync(bcnt, 0, MAXB * 4, stream);
    k_bhist<<<nbk, 256, 0, stream>>>(dst, bcnt, E);
    k_bscan<<<1, 64, 0, stream>>>(bcnt, bbase, gcur, nb);
    k_bin<<<nbk, 256, 0, stream>>>(src, dst, gcur, ebuf, E);
    k_nhist<<<nb, 256, 0, stream>>>(ebuf, bbase, rowptr, N);
    int nch = (N + 2047) / 2048;
    k_scan1<<<nch, 256, 0, stream>>>(rowptr, chunkSum, N);
    k_scan2<<<1, 64, 0, stream>>>(chunkSum, chunkOff, nch, rowptr + N);
    k_scan3<<<(N + 255) / 256, 256, 0, stream>>>(rowptr, chunkOff, N);
    k_bfill<<<nb, 256, 0, stream>>>(ebuf, bbase, rowptr, ssrc, N);

    // ---- weight prep ----
    k_wprep<256, 256><<<(256 * 256 + 255) / 256, 256, 0, stream>>>(Wl0, Wr0, Wt0);
    k_wprep<128, 256><<<(128 * 256 + 255) / 256, 256, 0, stream>>>(Wl1, Wr1, Wt1);
    k_wprep<128, 128><<<(128 * 128 + 255) / 256, 256, 0, stream>>>(Wl2, Wr2, Wt2);

    const int gGrid = (N + 63) / 64;

    // ---- layer 0 ----
    k_gemmM<256, 256, true><<<gGrid, 256, 0, stream>>>(x, Wt0, b0, xl, xr, N);
    k_agg<128, 0><<<(N + 31) / 32, 256, 0, stream>>>((const half8*)xl, (const half8*)xr,
                                                     rowptr, ssrc, nullptr, nullptr, h0, N);

    // ---- layer 1 ----
    k_gemmM<128, 256, false><<<gGrid, 256, 0, stream>>>(h0, Wt1, b1, xl, xr, N);
    k_agg<128, 1><<<(N + 31) / 32, 256, 0, stream>>>((const half8*)xl, (const half8*)xr,
                                                     rowptr, ssrc, out1, g, gb, N);

    // ---- layer 2 ----
    k_gemmM<128, 128, false><<<gGrid, 256, 0, stream>>>(gb, Wt2, b2, xl, xr, N);
    k_agg<64, 2><<<(N + 63) / 64, 256, 0, stream>>>((const half8*)xl, (const half8*)xr,
                                                    rowptr, ssrc, x_final, nullptr, nullptr, N);
}

// Round 2
// 578.578 us; speedup vs baseline: 1.3058x; 1.1627x over previous
//
#include <hip/hip_runtime.h>
#include <stdint.h>

typedef __attribute__((ext_vector_type(4))) float f32x4;
typedef _Float16 half8 __attribute__((ext_vector_type(8)));
typedef _Float16 half4 __attribute__((ext_vector_type(4)));

// ---------------- CSR build via bucket binning ----------------

#define BIN_CHUNK 8192   // edges per block, 32/thread
#define MAXB 512         // >= nb = ceil(N/256)

__global__ __launch_bounds__(256) void k_bhist(const int* __restrict__ dst,
                                               int* __restrict__ bcnt, int E) {
    __shared__ int lh[MAXB];
    for (int i = threadIdx.x; i < MAXB; i += 256) lh[i] = 0;
    __syncthreads();
    const int base = blockIdx.x * BIN_CHUNK;
#pragma unroll 4
    for (int i = 0; i < BIN_CHUNK / 256; i++) {
        int e = base + i * 256 + threadIdx.x;
        if (e < E) atomicAdd(&lh[dst[e] >> 8], 1);
    }
    __syncthreads();
    for (int i = threadIdx.x; i < MAXB; i += 256)
        if (lh[i]) atomicAdd(&bcnt[i], lh[i]);
}

__global__ void k_bscan(const int* __restrict__ bcnt, int* __restrict__ bbase,
                        int* __restrict__ gcur, int nb) {
    if (threadIdx.x == 0 && blockIdx.x == 0) {
        int run = 0;
        for (int i = 0; i < nb; i++) { bbase[i] = run; gcur[i] = run; run += bcnt[i]; }
        bbase[nb] = run;
    }
}

__global__ __launch_bounds__(256) void k_bin(const int* __restrict__ src,
                                             const int* __restrict__ dst,
                                             int* __restrict__ gcur,
                                             unsigned* __restrict__ ebuf, int E) {
    __shared__ int lh[MAXB];
    __shared__ int lcur[MAXB];
    for (int i = threadIdx.x; i < MAXB; i += 256) lh[i] = 0;
    __syncthreads();
    const int base = blockIdx.x * BIN_CHUNK;
#pragma unroll 4
    for (int i = 0; i < BIN_CHUNK / 256; i++) {
        int e = base + i * 256 + threadIdx.x;
        if (e < E) atomicAdd(&lh[dst[e] >> 8], 1);
    }
    __syncthreads();
    for (int i = threadIdx.x; i < MAXB; i += 256)
        lcur[i] = lh[i] ? atomicAdd(&gcur[i], lh[i]) : 0;
    __syncthreads();
#pragma unroll 4
    for (int i = 0; i < BIN_CHUNK / 256; i++) {
        int e = base + i * 256 + threadIdx.x;
        if (e < E) {
            int d = dst[e];
            int pos = atomicAdd(&lcur[d >> 8], 1);
            ebuf[pos] = (unsigned)src[e] | ((unsigned)(d & 255) << 24);
        }
    }
}

__global__ __launch_bounds__(256) void k_nhist(const unsigned* __restrict__ ebuf,
                                               const int* __restrict__ bbase,
                                               int* __restrict__ deg, int N) {
    __shared__ int cnt[256];
    cnt[threadIdx.x] = 0;
    __syncthreads();
    const int b = blockIdx.x;
    const int lo = bbase[b], hi = bbase[b + 1];
    for (int e = lo + threadIdx.x; e < hi; e += 256)
        atomicAdd(&cnt[ebuf[e] >> 24], 1);
    __syncthreads();
    int n = (b << 8) + threadIdx.x;
    if (n < N) deg[n] = cnt[threadIdx.x];
}

__global__ __launch_bounds__(256) void k_bfill(const unsigned* __restrict__ ebuf,
                                               const int* __restrict__ bbase,
                                               const int* __restrict__ rowptr,
                                               int* __restrict__ ssrc, int N) {
    __shared__ int lc[256];
    const int b = blockIdx.x;
    int n = (b << 8) + threadIdx.x;
    lc[threadIdx.x] = (n < N) ? rowptr[n] : 0;
    __syncthreads();
    const int lo = bbase[b], hi = bbase[b + 1];
    for (int e = lo + threadIdx.x; e < hi; e += 256) {
        unsigned v = ebuf[e];
        int pos = atomicAdd(&lc[v >> 24], 1);
        ssrc[pos] = (int)(v & 0xFFFFFFu);
    }
}

// ---------------- rowptr scan ----------------

__global__ void k_scan1(int* __restrict__ buf, int* __restrict__ chunkSum, int N) {
    const int t = threadIdx.x;
    const int base = blockIdx.x * 2048 + t * 8;
    int v[8];
    int s = 0;
#pragma unroll
    for (int i = 0; i < 8; i++) {
        int idx = base + i;
        v[i] = (idx < N) ? buf[idx] : 0;
        s += v[i];
    }
    __shared__ int sh[256];
    sh[t] = s;
    __syncthreads();
    for (int off = 1; off < 256; off <<= 1) {
        int add = (t >= off) ? sh[t - off] : 0;
        __syncthreads();
        sh[t] += add;
        __syncthreads();
    }
    int excl = sh[t] - s;
    int run = excl;
#pragma unroll
    for (int i = 0; i < 8; i++) {
        int idx = base + i;
        if (idx < N) buf[idx] = run;
        run += v[i];
    }
    if (t == 255) chunkSum[blockIdx.x] = sh[255];
}

__global__ void k_scan2(const int* __restrict__ chunkSum, int* __restrict__ chunkOff,
                        int nch, int* __restrict__ rowptrN) {
    if (threadIdx.x == 0 && blockIdx.x == 0) {
        int run = 0;
        for (int i = 0; i < nch; i++) { chunkOff[i] = run; run += chunkSum[i]; }
        *rowptrN = run;
    }
}

__global__ void k_scan3(int* __restrict__ rowptr, const int* __restrict__ chunkOff, int N) {
    int i = blockIdx.x * 256 + threadIdx.x;
    if (i < N) rowptr[i] += chunkOff[i >> 11];
}

// ---------------- weight prep: k-blocked layout ----------------
// Wt[(k>>5)*(NCOLT*32) + n*32 + (k&31)] = f16( n<NCOL ? Wl[k][n] : Wr[k][n-NCOL] )
// With this layout a wave's b[t] fragment load (l16*64B + quad*16B) covers one
// contiguous 1 KiB region -> fully coalesced.

template <int K, int NCOLT>
__global__ void k_wprep(const float* __restrict__ Wl, const float* __restrict__ Wr,
                        _Float16* __restrict__ Wt) {
    constexpr int NCOL = NCOLT / 2;
    int i = blockIdx.x * 256 + threadIdx.x;
    if (i < K * NCOLT) {
        int n = i / K, k = i - n * K;
        float v = (n < NCOL) ? Wl[(size_t)k * NCOL + n] : Wr[(size_t)k * NCOL + (n - NCOL)];
        Wt[(size_t)(k >> 5) * (NCOLT * 32) + n * 32 + (k & 31)] = (_Float16)v;
    }
}

// ---------------- MFMA GEMM: [Cl|Cr] = A @ [Wl|Wr] ----------------
// Block: 256 thr = 4 waves, M-tile 64. Wave w owns cols [w*WC, (w+1)*WC).
// A staged f32/f16 -> f16 LDS (coalesced, +8-half pad breaks bank aliasing).
// MFMA called with SWAPPED operands mfma(b, a, acc):
//   acc[rg][t][r] = C[m0 + rg*16 + l16][colbase + t*16 + quad*4 + r]
// so each lane owns 4 consecutive columns of one row -> 8B vector epilogue.
// C staged through LDS (reusing A buffer) -> fully coalesced global stores.

template <int K, int NCOLT, bool AF32>
__global__ __launch_bounds__(256) void k_gemmM(const void* __restrict__ Av,
                                               const _Float16* __restrict__ Wt,
                                               const float* __restrict__ bias,
                                               _Float16* __restrict__ Cl,
                                               _Float16* __restrict__ Cr, int M) {
    constexpr int NCOL = NCOLT / 2;
    constexpr int WC = NCOLT / 4;
    constexpr int NT = WC / 16;
    constexpr int AS = K + 8;      // A-tile LDS row stride (halves)
    constexpr int CS = NCOLT + 8;  // C-tile LDS row stride (halves)
    constexpr int MAXS = (K > NCOLT ? K : NCOLT) + 8;
    __shared__ _Float16 sh[64 * MAXS];

    const int tid = threadIdx.x;
    const int lane = tid & 63;
    const int wave = tid >> 6;
    const int quad = lane >> 4;
    const int l16 = lane & 15;
    const int m0 = blockIdx.x * 64;
    const int colbase = wave * WC;

    // ---- stage A into LDS (block-wide coalesced: 4 KiB per instruction) ----
    if (AF32) {
        const float* A = (const float*)Av;
#pragma unroll
        for (int i = 0; i < K / 16; i++) {
            int off = i * 1024 + tid * 4;
            int row = off / K, col = off % K;
            f32x4 u = {0.f, 0.f, 0.f, 0.f};
            if (m0 + row < M) u = *(const f32x4*)(A + (size_t)(m0 + row) * K + col);
            half4 h = {(_Float16)u[0], (_Float16)u[1], (_Float16)u[2], (_Float16)u[3]};
            *(half4*)(sh + row * AS + col) = h;
        }
    } else {
        const _Float16* A = (const _Float16*)Av;
#pragma unroll
        for (int i = 0; i < K / 32; i++) {
            int off = i * 2048 + tid * 8;
            int row = off / K, col = off % K;
            half8 u = {0, 0, 0, 0, 0, 0, 0, 0};
            if (m0 + row < M) u = *(const half8*)(A + (size_t)(m0 + row) * K + col);
            *(half8*)(sh + row * AS + col) = u;
        }
    }
    __syncthreads();

    f32x4 acc[4][NT];
#pragma unroll
    for (int rg = 0; rg < 4; rg++)
#pragma unroll
        for (int t = 0; t < NT; t++) acc[rg][t] = (f32x4){0.f, 0.f, 0.f, 0.f};

#pragma unroll
    for (int k0 = 0; k0 < K; k0 += 32) {
        half8 a[4];
#pragma unroll
        for (int rg = 0; rg < 4; rg++)
            a[rg] = *(const half8*)(sh + (rg * 16 + l16) * AS + k0 + quad * 8);
        half8 b[NT];
        const _Float16* Wk = Wt + (size_t)(k0 >> 5) * (NCOLT * 32);
#pragma unroll
        for (int t = 0; t < NT; t++)
            b[t] = *(const half8*)(Wk + (colbase + t * 16 + l16) * 32 + quad * 8);
#pragma unroll
        for (int rg = 0; rg < 4; rg++)
#pragma unroll
            for (int t = 0; t < NT; t++)
                acc[rg][t] = __builtin_amdgcn_mfma_f32_16x16x32_f16(b[t], a[rg], acc[rg][t], 0, 0, 0);
    }

    __syncthreads();  // done reading A-tile; reuse sh as C-tile

    // ---- epilogue: acc -> f16 C-tile in LDS (8B vector writes) ----
#pragma unroll
    for (int t = 0; t < NT; t++) {
        int c0 = colbase + t * 16 + quad * 4;
        f32x4 bv = {0.f, 0.f, 0.f, 0.f};
        if (c0 >= NCOL) bv = *(const f32x4*)(bias + (c0 - NCOL));
#pragma unroll
        for (int rg = 0; rg < 4; rg++) {
            half4 h = {(_Float16)(acc[rg][t][0] + bv[0]), (_Float16)(acc[rg][t][1] + bv[1]),
                       (_Float16)(acc[rg][t][2] + bv[2]), (_Float16)(acc[rg][t][3] + bv[3])};
            *(half4*)(sh + (rg * 16 + l16) * CS + c0) = h;
        }
    }
    __syncthreads();

    // ---- coalesced global stores (full 64B lines) ----
#pragma unroll
    for (int i = 0; i < (64 * NCOL) / 2048; i++) {
        int off = i * 2048 + tid * 8;
        int row = off / NCOL, col = off % NCOL;
        if (m0 + row < M) {
            *(half8*)(Cl + (size_t)(m0 + row) * NCOL + col) = *(const half8*)(sh + row * CS + col);
            *(half8*)(Cr + (size_t)(m0 + row) * NCOL + col) = *(const half8*)(sh + row * CS + NCOL + col);
        }
    }
}

// ---------------- aggregation ----------------

template <int COUT, int MODE>
__global__ __launch_bounds__(256) void k_agg(const half8* __restrict__ xl,
                                             const half8* __restrict__ xr,
                                             const int* __restrict__ rowptr,
                                             const int* __restrict__ ssrc,
                                             float* __restrict__ outF1,
                                             float* __restrict__ outF2,
                                             _Float16* __restrict__ outH, int N) {
    constexpr int LPN = COUT / 16;
    constexpr int NPB = 256 / LPN;
    constexpr int C8 = COUT / 8;
    const int tid = threadIdx.x;
    const int c = tid % LPN;
    const int n = blockIdx.x * NPB + tid / LPN;
    if (n >= N) return;

    const int rp0 = rowptr[n];
    const int rp1 = rowptr[n + 1];
    float acc[16];
#pragma unroll
    for (int i = 0; i < 16; i++) acc[i] = 0.f;

    const size_t cb = (size_t)c * 2;
    int e = rp0;
    for (; e + 3 < rp1; e += 4) {
        int s0 = ssrc[e], s1 = ssrc[e + 1], s2 = ssrc[e + 2], s3 = ssrc[e + 3];
        half8 v0a = xl[(size_t)s0 * C8 + cb], v0b = xl[(size_t)s0 * C8 + cb + 1];
        half8 v1a = xl[(size_t)s1 * C8 + cb], v1b = xl[(size_t)s1 * C8 + cb + 1];
        half8 v2a = xl[(size_t)s2 * C8 + cb], v2b = xl[(size_t)s2 * C8 + cb + 1];
        half8 v3a = xl[(size_t)s3 * C8 + cb], v3b = xl[(size_t)s3 * C8 + cb + 1];
#pragma unroll
        for (int i = 0; i < 8; i++) {
            acc[i] += (float)v0a[i] + (float)v1a[i] + (float)v2a[i] + (float)v3a[i];
            acc[8 + i] += (float)v0b[i] + (float)v1b[i] + (float)v2b[i] + (float)v3b[i];
        }
    }
    for (; e < rp1; e++) {
        int s = ssrc[e];
        half8 va = xl[(size_t)s * C8 + cb], vb = xl[(size_t)s * C8 + cb + 1];
#pragma unroll
        for (int i = 0; i < 8; i++) {
            acc[i] += (float)va[i];
            acc[8 + i] += (float)vb[i];
        }
    }

    const int deg = rp1 - rp0;
    const float scale = 1.0f / (float)(deg > 1 ? deg : 1);
    half8 x0 = xr[(size_t)n * C8 + cb];
    half8 x1 = xr[(size_t)n * C8 + cb + 1];
    float res[16];
#pragma unroll
    for (int i = 0; i < 8; i++) {
        res[i] = acc[i] * scale + (float)x0[i];
        res[8 + i] = acc[8 + i] * scale + (float)x1[i];
    }

    const size_t ob = (size_t)n * COUT + (size_t)c * 16;
    if (MODE == 0) {
        half8 h0v, h1v;
#pragma unroll
        for (int i = 0; i < 8; i++) {
            h0v[i] = (_Float16)(res[i] > 0.f ? res[i] : 0.f);
            h1v[i] = (_Float16)(res[8 + i] > 0.f ? res[8 + i] : 0.f);
        }
        *(half8*)(outH + ob) = h0v;
        *(half8*)(outH + ob + 8) = h1v;
    } else if (MODE == 1) {
#pragma unroll
        for (int q = 0; q < 4; q++) {
            f32x4 v = {res[q * 4], res[q * 4 + 1], res[q * 4 + 2], res[q * 4 + 3]};
            *(f32x4*)(outF1 + ob + q * 4) = v;
            f32x4 z = {v[0] > 0.f ? v[0] : 0.f, v[1] > 0.f ? v[1] : 0.f,
                       v[2] > 0.f ? v[2] : 0.f, v[3] > 0.f ? v[3] : 0.f};
            *(f32x4*)(outF2 + ob + q * 4) = z;
        }
        half8 h0v, h1v;
#pragma unroll
        for (int i = 0; i < 8; i++) {
            h0v[i] = (_Float16)(res[i] > 0.f ? res[i] : 0.f);
            h1v[i] = (_Float16)(res[8 + i] > 0.f ? res[8 + i] : 0.f);
        }
        *(half8*)(outH + ob) = h0v;
        *(half8*)(outH + ob + 8) = h1v;
    } else {
#pragma unroll
        for (int q = 0; q < 4; q++) {
            f32x4 v = {res[q * 4], res[q * 4 + 1], res[q * 4 + 2], res[q * 4 + 3]};
            *(f32x4*)(outF1 + ob + q * 4) = v;
        }
    }
}

// ---------------- launch ----------------

extern "C" void kernel_launch(void* const* d_in, const int* in_sizes, int n_in,
                              void* d_out, int out_size, void* d_ws, size_t ws_size,
                              hipStream_t stream) {
    const float* x   = (const float*)d_in[0];
    const int*   ei  = (const int*)d_in[1];
    const float* Wl0 = (const float*)d_in[2];
    const float* Wr0 = (const float*)d_in[3];
    const float* b0  = (const float*)d_in[4];
    const float* Wl1 = (const float*)d_in[5];
    const float* Wr1 = (const float*)d_in[6];
    const float* b1  = (const float*)d_in[7];
    const float* Wl2 = (const float*)d_in[8];
    const float* Wr2 = (const float*)d_in[9];
    const float* b2  = (const float*)d_in[10];

    const int N = in_sizes[0] / 256;   // 100000
    const int E = in_sizes[1] / 2;     // 1600000
    const int* src = ei;
    const int* dst = ei + E;

    char* p = (char*)d_ws;
    auto alloc = [&](size_t bytes) -> void* {
        void* r = (void*)p;
        p += (bytes + 255) & ~(size_t)255;
        return r;
    };
    int*      rowptr   = (int*)alloc((size_t)(N + 1) * 4);
    int*      chunkSum = (int*)alloc(64 * 4);
    int*      chunkOff = (int*)alloc(64 * 4);
    int*      bcnt     = (int*)alloc(MAXB * 4);
    int*      bbase    = (int*)alloc((MAXB + 1) * 4);
    int*      gcur     = (int*)alloc(MAXB * 4);
    int*      ssrc     = (int*)alloc((size_t)E * 4);
    _Float16* xl       = (_Float16*)alloc((size_t)N * 128 * 2);
    _Float16* xr       = (_Float16*)alloc((size_t)N * 128 * 2);
    _Float16* h0       = (_Float16*)alloc((size_t)N * 128 * 2);
    _Float16* gb       = (_Float16*)alloc((size_t)N * 128 * 2);
    _Float16* Wt0      = (_Float16*)alloc((size_t)256 * 256 * 2);
    _Float16* Wt1      = (_Float16*)alloc((size_t)256 * 128 * 2);
    _Float16* Wt2      = (_Float16*)alloc((size_t)128 * 128 * 2);

    // ebuf (binned packed edges, E*4 bytes) aliases gb: dead before gb's first
    // write (layer-1 agg), stream-ordered so no hazard.
    unsigned* ebuf = (unsigned*)gb;

    float* out = (float*)d_out;
    float* x_final = out;                      // N*64
    float* out1    = out + (size_t)N * 64;     // N*128
    float* g       = out + (size_t)N * 192;    // N*128

    const int nb = (N + 255) >> 8;             // buckets of 256 nodes
    const int nbk = (E + BIN_CHUNK - 1) / BIN_CHUNK;

    // ---- CSR build (binned) ----
    hipMemsetAsync(bcnt, 0, MAXB * 4, stream);
    k_bhist<<<nbk, 256, 0, stream>>>(dst, bcnt, E);
    k_bscan<<<1, 64, 0, stream>>>(bcnt, bbase, gcur, nb);
    k_bin<<<nbk, 256, 0, stream>>>(src, dst, gcur, ebuf, E);
    k_nhist<<<nb, 256, 0, stream>>>(ebuf, bbase, rowptr, N);
    int nch = (N + 2047) / 2048;
    k_scan1<<<nch, 256, 0, stream>>>(rowptr, chunkSum, N);
    k_scan2<<<1, 64, 0, stream>>>(chunkSum, chunkOff, nch, rowptr + N);
    k_scan3<<<(N + 255) / 256, 256, 0, stream>>>(rowptr, chunkOff, N);
    k_bfill<<<nb, 256, 0, stream>>>(ebuf, bbase, rowptr, ssrc, N);

    // ---- weight prep ----
    k_wprep<256, 256><<<(256 * 256 + 255) / 256, 256, 0, stream>>>(Wl0, Wr0, Wt0);
    k_wprep<128, 256><<<(128 * 256 + 255) / 256, 256, 0, stream>>>(Wl1, Wr1, Wt1);
    k_wprep<128, 128><<<(128 * 128 + 255) / 256, 256, 0, stream>>>(Wl2, Wr2, Wt2);

    const int gGrid = (N + 63) / 64;

    // ---- layer 0 ----
    k_gemmM<256, 256, true><<<gGrid, 256, 0, stream>>>(x, Wt0, b0, xl, xr, N);
    k_agg<128, 0><<<(N + 31) / 32, 256, 0, stream>>>((const half8*)xl, (const half8*)xr,
                                                     rowptr, ssrc, nullptr, nullptr, h0, N);

    // ---- layer 1 ----
    k_gemmM<128, 256, false><<<gGrid, 256, 0, stream>>>(h0, Wt1, b1, xl, xr, N);
    k_agg<128, 1><<<(N + 31) / 32, 256, 0, stream>>>((const half8*)xl, (const half8*)xr,
                                                     rowptr, ssrc, out1, g, gb, N);

    // ---- layer 2 ----
    k_gemmM<128, 128, false><<<gGrid, 256, 0, stream>>>(gb, Wt2, b2, xl, xr, N);
    k_agg<64, 2><<<(N + 63) / 64, 256, 0, stream>>>((const half8*)xl, (const half8*)xr,
                                                    rowptr, ssrc, x_final, nullptr, nullptr, N);
}